// Round 6
// baseline (434.478 us; speedup 1.0000x reference)
//
#include <hip/hip_runtime.h>

// Input:  x[b][c][h][w], B=8, C=32, H=512, W=512 (fp32)
// Output: out[b][q][c][h2][w2], q in {LL,LH,HL,HH}, h2=256, w2=256 (fp32)
//
// R5 structure (LDS s/d planes, wave q -> quadrant q, contiguous burst stores)
// + cross-tile software pipeline: 4 tiles per block, prefetch tile k+1 into
// registers BEFORE tile k's store phase, raw s_barrier (no implicit
// vmcnt(0)/lgkmcnt(0) drain like __syncthreads) with explicit lgkmcnt waits.
// The wait for prefetched regs is vmcnt(8) (8 stores outstanding), so the
// read stream stays in flight underneath the write stream at all times.

#define C_    32
#define NBLK_ 2048
#define TPB_  4          // tiles per block; NBLK_*TPB_ = 8192 tiles total

typedef float v4f __attribute__((ext_vector_type(4)));

__global__ __launch_bounds__(256)
void WaveletTransform_14319420965150_kernel(const float* __restrict__ x,
                                            float* __restrict__ out) {
    __shared__ v4f sd[2][16][64];          // s/d planes, 32 KiB

    const v4f* __restrict__ xin = (const v4f*)x;
    v4f* __restrict__ o         = (v4f*)out;

    const int t    = threadIdx.x;
    const int lane = t & 63;
    const int wid  = t >> 6;               // 0..3
    const int q    = wid;                  // quadrant owned by this wave
    const int p    = q >> 1;               // 0: s-plane, 1: d-plane
    const bool neg = (q & 1);

    v4f a[4], b[4];

    // ---------------- prologue: load + stage tile 0 ----------------
    int tb = blockIdx.x;
    {
        const int bc = tb >> 5, h2b = tb & 31;
        const size_t imgbase = (size_t)bc * 65536 + (size_t)h2b * 2048;
        #pragma unroll
        for (int j = 0; j < 4; ++j) {
            const size_t g = imgbase + (size_t)(4 * j + wid) * 128 + 2 * lane;
            a[j] = xin[g]; b[j] = xin[g + 1];
        }
        #pragma unroll
        for (int j = 0; j < 4; ++j) {
            const int r = 4 * j + wid;
            v4f s = { a[j].x + a[j].y, a[j].z + a[j].w,
                      b[j].x + b[j].y, b[j].z + b[j].w };
            v4f d = { a[j].x - a[j].y, a[j].z - a[j].w,
                      b[j].x - b[j].y, b[j].z - b[j].w };
            sd[0][r][lane] = s;
            sd[1][r][lane] = d;
        }
    }
    asm volatile("s_waitcnt lgkmcnt(0)" ::: "memory");
    __builtin_amdgcn_s_barrier();
    __builtin_amdgcn_sched_barrier(0);

    #pragma unroll
    for (int k = 0; k < TPB_; ++k) {
        const int tb_next = tb + NBLK_;

        if (k < TPB_ - 1) {
            // prefetch tile k+1 into registers — issued BEFORE the stores so
            // the later wait on a[]/b[] is vmcnt(8), never a store drain
            const int bc = tb_next >> 5, h2b = tb_next & 31;
            const size_t imgbase = (size_t)bc * 65536 + (size_t)h2b * 2048;
            #pragma unroll
            for (int j = 0; j < 4; ++j) {
                const size_t g = imgbase + (size_t)(4 * j + wid) * 128 + 2 * lane;
                a[j] = xin[g]; b[j] = xin[g + 1];
            }
            __builtin_amdgcn_sched_barrier(0);   // pin: loads precede stores
        }

        // -------- consume: wave q stores quadrant q of tile k --------
        {
            const int bc = tb >> 5, h2b = tb & 31;
            size_t ob = ((size_t)(bc >> 5) * 128 + (size_t)q * C_ + (bc & (C_ - 1))) * 16384
                      + (size_t)(h2b * 8) * 64 + lane;
            #pragma unroll
            for (int r = 0; r < 8; ++r) {
                v4f top = sd[p][2 * r][lane];       // contiguous b128, conflict-free
                v4f bot = sd[p][2 * r + 1][lane];
                v4f res = neg ? (top - bot) * 0.5f : (top + bot) * 0.5f;
                o[ob + (size_t)r * 64] = res;       // 8 KB/wave single stream
            }
        }

        if (k < TPB_ - 1) {
            __builtin_amdgcn_sched_barrier(0);
            __builtin_amdgcn_s_barrier();           // all waves done reading sd
            __builtin_amdgcn_sched_barrier(0);
            // -------- stage tile k+1 (waits only on the prefetch loads) ----
            #pragma unroll
            for (int j = 0; j < 4; ++j) {
                const int r = 4 * j + wid;
                v4f s = { a[j].x + a[j].y, a[j].z + a[j].w,
                          b[j].x + b[j].y, b[j].z + b[j].w };
                v4f d = { a[j].x - a[j].y, a[j].z - a[j].w,
                          b[j].x - b[j].y, b[j].z - b[j].w };
                sd[0][r][lane] = s;
                sd[1][r][lane] = d;
            }
            asm volatile("s_waitcnt lgkmcnt(0)" ::: "memory");
            __builtin_amdgcn_s_barrier();           // writes visible to all waves
            __builtin_amdgcn_sched_barrier(0);
        }
        tb = tb_next;
    }
}

extern "C" void kernel_launch(void* const* d_in, const int* in_sizes, int n_in,
                              void* d_out, int out_size, void* d_ws, size_t ws_size,
                              hipStream_t stream) {
    const float* x = (const float*)d_in[0];
    float* out = (float*)d_out;
    const int block = 256;
    WaveletTransform_14319420965150_kernel<<<NBLK_, block, 0, stream>>>(x, out);
}